// Round 11
// baseline (247.572 us; speedup 1.0000x reference)
//
#include <hip/hip_runtime.h>
#include <hip/hip_bf16.h>
#include <math.h>
#include <type_traits>

// Problem constants (fixed by setup_inputs)
#define BATCH 8
#define QLEN 900
#define HEADS 8
#define LEVELS 4
#define POINTS 4
#define NUM_KEYS 13294
#define BQ (BATCH * QLEN)          // 7200
#define MROWS_V (BATCH * NUM_KEYS) // 106352
#define VTILES (MROWS_V / 16)      // 6647 16-row tiles (exact)
#define VBLOCKS 512
#define TPB 13                     // ceil(6647/512)

__constant__ const int c_LH[4] = {100, 50, 25, 13};
__constant__ const int c_LW[4] = {100, 50, 25, 13};
__constant__ const int c_LS[4] = {0, 10000, 12500, 13125};

typedef __attribute__((ext_vector_type(8))) short bfrag;   // 8 bf16
typedef __attribute__((ext_vector_type(4))) float ffrag;   // 4 fp32 acc

static __device__ __forceinline__ unsigned short f2bf(float f) {
    __hip_bfloat16 h = __float2bfloat16(f);
    return *(unsigned short*)&h;
}
static __device__ __forceinline__ float bf2f(unsigned int u16) {
    unsigned int v = u16 << 16;
    float f;
    __builtin_memcpy(&f, &v, 4);
    return f;
}

// direct global->LDS DMA, 16B per lane. LDS dest = base + lane*16 (linear,
// wave-uniform base); global src is per-lane (pre-swizzled for bank-conflict-
// free reads later — rule 21: swizzle the SOURCE, keep LDS linear).
typedef __attribute__((address_space(1))) void* as1_vp;
typedef __attribute__((address_space(3))) void* as3_vp;
static __device__ __forceinline__ void gload16(const void* g, void* l) {
    __builtin_amdgcn_global_load_lds((as1_vp)(void*)g, (as3_vp)l, 16, 0, 0);
}

// ---------------------------------------------------------------------------
// Merged prep: cast+transpose all three weight matrices to bf16 [n][k],
// concat off/attn biases. One launch instead of five.
// ---------------------------------------------------------------------------
__global__ __launch_bounds__(256)
void prep_kernel(const float* __restrict__ W_val, const float* __restrict__ W_off,
                 const float* __restrict__ W_attn, const float* __restrict__ W_out,
                 const float* __restrict__ b_off, const float* __restrict__ b_attn,
                 unsigned short* __restrict__ Wv, unsigned short* __restrict__ Woa,
                 unsigned short* __restrict__ Wo, float* __restrict__ boa) {
    const int id = blockIdx.x * 256 + threadIdx.x;
    if (id < 65536) {
        const int n = id >> 8, k = id & 255;
        Wv[id] = f2bf(W_val[k * 256 + n]);
    } else if (id < 131072) {
        const int t = id - 65536;
        const int n = t >> 8, k = t & 255;
        Woa[t] = f2bf(W_off[k * 256 + n]);
    } else if (id < 163840) {
        const int t = id - 131072;
        const int n = t >> 8, k = t & 255;       // n in 0..127
        Woa[65536 + t] = f2bf(W_attn[k * 128 + n]);
    } else if (id < 229376) {
        const int t = id - 163840;
        const int n = t >> 8, k = t & 255;
        Wo[t] = f2bf(W_out[k * 256 + n]);
    } else if (id < 229760) {
        const int t = id - 229376;
        boa[t] = (t < 256) ? b_off[t] : b_attn[t - 256];
    }
}

// ---------------------------------------------------------------------------
// Value-projection GEMM v8: C = bf16(A @ Wv + bias), HEAD-MAJOR [b][h][key][32].
// Round-11 change vs v7: A staged as RAW F32 via global_load_lds width=16
// (the m97 ladder's +69% lever, never tried here because reg-staging was
// forced by the f32->bf16 cvt). Conversion moves to fragment-read time
// (2x ds_read_b128 + 8 cvt per frag; VALUBusy was 6% — headroom).
//  * LDS dest linear (HW: base + lane*16); bank-swizzle moved to the GLOBAL
//    source: lane reads 16B chunk (lane ^ (row&7)) of its 1KB row-segment —
//    still one contiguous coalesced 1KB/instruction (rule 21).
//  * Read side: chunk c of row r lives at LDS byte r*1024 + (c^(r&7))*16;
//    same conflict structure as v7's proven bf16 pattern.
//  * Sync: counted vmcnt ONLY. Prologue vmcnt(2); steady state vmcnt(10)
//    (= 2 next-next-tile loads + 8 stores allowed outstanding; in-order
//    vmcnt retirement makes the count robust to load/store interleave).
//    One raw s_barrier per tile; never a drain. No ds_writes at all.
//  * Ring: 3 x 16KB = 48KB; 512 thr / 8 waves x 32 cols; b[2][8] = 64 VGPR.
// ---------------------------------------------------------------------------
__global__ __launch_bounds__(512, 4)
void gemm_val_stream(const float* __restrict__ A, const unsigned short* __restrict__ WT,
                     const float* __restrict__ bias, unsigned short* __restrict__ C) {
    __shared__ __align__(16) float Abuf[3][16 * 256];   // 3 x 16KB f32 tiles
    const int tid = threadIdx.x;
    const int wave = tid >> 6;
    const int lane = tid & 63;
    const int ln = lane & 15;
    const int quad = lane >> 4;
    const int n0 = wave * 32;           // wave covers one 32-col head slice

    // persistent B fragments: 2 n-tiles x 8 k-steps (64 VGPR)
    bfrag b[2][8];
#pragma unroll
    for (int j = 0; j < 2; ++j) {
        const unsigned short* bp = WT + (size_t)(n0 + j * 16 + ln) * 256 + quad * 8;
#pragma unroll
        for (int ks = 0; ks < 8; ++ks) b[j][ks] = *(const bfrag*)(bp + ks * 32);
    }
    float bj[2];
#pragma unroll
    for (int j = 0; j < 2; ++j) bj[j] = bias[n0 + j * 16 + ln];

    const int t0 = blockIdx.x * TPB;
    const int t1 = min(t0 + TPB, VTILES);
    if (t0 >= t1) return;

    // staging offsets: wave handles rows j = wave*2 + i (i=0,1) of the tile.
    // global per-lane byte: j*1024 + (lane ^ (j&7))*16  (contiguous 1KB/instr)
    // lds uniform base byte: j*1024
    int goff[2], loff[2];
#pragma unroll
    for (int i = 0; i < 2; ++i) {
        const int j = wave * 2 + i;
        goff[i] = j * 1024 + ((lane ^ (j & 7)) << 4);
        loff[i] = j * 1024;
    }

    const char* Ab = (const char*)A;
    char* lds0 = (char*)&Abuf[0][0];

    // prologue: issue t0 and t0+1 loads; wait t0 (allow t0+1's 2); barrier.
#pragma unroll
    for (int i = 0; i < 2; ++i)
        gload16(Ab + (size_t)t0 * 16384 + goff[i], lds0 + loff[i]);
    if (t0 + 1 < t1) {
#pragma unroll
        for (int i = 0; i < 2; ++i)
            gload16(Ab + (size_t)(t0 + 1) * 16384 + goff[i], lds0 + 16384 + loff[i]);
    }
    asm volatile("s_waitcnt vmcnt(2)" ::: "memory");
    __builtin_amdgcn_s_barrier();

    int rb = 0;
    for (int t = t0; t < t1; ++t) {
        const char* abuf = lds0 + rb * 16384;
        ffrag acc[2];
#pragma unroll
        for (int j = 0; j < 2; ++j) acc[j] = (ffrag){0.f, 0.f, 0.f, 0.f};
#pragma unroll
        for (int ks = 0; ks < 8; ++ks) {
            const int c0 = ks * 8 + quad * 2;
            const float4 f0 = *(const float4*)(abuf + ln * 1024 + ((c0 ^ (ln & 7)) << 4));
            const float4 f1 = *(const float4*)(abuf + ln * 1024 + (((c0 + 1) ^ (ln & 7)) << 4));
            unsigned short u[8] = {f2bf(f0.x), f2bf(f0.y), f2bf(f0.z), f2bf(f0.w),
                                   f2bf(f1.x), f2bf(f1.y), f2bf(f1.z), f2bf(f1.w)};
            const bfrag af = *(const bfrag*)u;
            acc[0] = __builtin_amdgcn_mfma_f32_16x16x32_bf16(af, b[0][ks], acc[0], 0, 0, 0);
            acc[1] = __builtin_amdgcn_mfma_f32_16x16x32_bf16(af, b[1][ks], acc[1], 0, 0, 0);
        }

        // issue loads for tile t+2 into slot (rb+2)%3
        if (t + 2 < t1) {
            char* dbuf = lds0 + ((rb + 2 >= 3) ? rb - 1 : rb + 2) * 16384;
#pragma unroll
            for (int i = 0; i < 2; ++i)
                gload16(Ab + (size_t)(t + 2) * 16384 + goff[i], dbuf + loff[i]);
        }

        // epilogue stores (8/thread), head-major [b][h][key][32]
        const int rowb = t * 16 + quad * 4;
#pragma unroll
        for (int r = 0; r < 4; ++r) {
            const unsigned row = rowb + r;
            const unsigned bb = row / NUM_KEYS;
            const unsigned key = row - bb * NUM_KEYS;
#pragma unroll
            for (int j = 0; j < 2; ++j) {
                const int col = n0 + j * 16 + ln;
                const int h = col >> 5, d = col & 31;
                C[((size_t)(bb * 8 + h) * NUM_KEYS + key) * 32 + d] =
                    f2bf(acc[j][r] + bj[j]);
            }
        }

        // wait until only {t+2 loads (2) + this iter's stores (8)} may remain
        // -> guarantees t+1's loads landed (they're older than everything).
        asm volatile("s_waitcnt vmcnt(10)" ::: "memory");
        __builtin_amdgcn_s_barrier();
        rb = (rb + 1 == 3) ? 0 : rb + 1;
    }
}

// ---------------------------------------------------------------------------
// bf16-MFMA GEMM: C[M,N] = bf16(A[M,256]) @ WT^T + bias.
// WT is [N][256] bf16 (pre-transposed). BM=64, BN=128, BK=64, 256 thr = 4 waves.
// Used for the offattn GEMM and the out-projection.
// ---------------------------------------------------------------------------
#define GST 72

template <typename AT, typename CT>
__global__ __launch_bounds__(256)
void gemm_mfma(const AT* __restrict__ A, const unsigned short* __restrict__ WT,
               const float* __restrict__ bias, CT* __restrict__ C,
               int M, int ldc) {
    __shared__ unsigned short As[64 * GST];
    __shared__ unsigned short Bs[128 * GST];
    const int tid = threadIdx.x;
    const int wave = tid >> 6;
    const int lane = tid & 63;
    const int ln = lane & 15;
    const int quad = lane >> 4;
    const int m0 = blockIdx.x * 64;
    const int n0 = blockIdx.y * 128;

    ffrag acc[8];
#pragma unroll
    for (int j = 0; j < 8; ++j) acc[j] = (ffrag){0.f, 0.f, 0.f, 0.f};

    const int ar = tid >> 2;            // A row in tile (0..63)
    const int akc = (tid & 3) * 16;     // A k-chunk (16 elems)
    const int brow = tid >> 1;          // B col in tile (0..127)
    const int bkc = (tid & 1) * 32;     // B k-chunk (32 elems)
    const bool a_ok = (m0 + ar) < M;
    const AT* a_src = A + (size_t)(m0 + ar) * 256 + akc;
    const unsigned short* b_src = WT + (size_t)(n0 + brow) * 256 + bkc;

    for (int k0 = 0; k0 < 256; k0 += 64) {
        // ---- stage A (64 x 64, -> bf16) ----
        unsigned short* adst = &As[ar * GST + akc];
        if constexpr (std::is_same<AT, float>::value) {
            float4 f0, f1, f2, f3;
            if (a_ok) {
                const float4* p = (const float4*)(a_src + k0);
                f0 = p[0]; f1 = p[1]; f2 = p[2]; f3 = p[3];
            } else {
                f0 = make_float4(0.f, 0.f, 0.f, 0.f);
                f1 = f0; f2 = f0; f3 = f0;
            }
            float v[16] = {f0.x, f0.y, f0.z, f0.w, f1.x, f1.y, f1.z, f1.w,
                           f2.x, f2.y, f2.z, f2.w, f3.x, f3.y, f3.z, f3.w};
            unsigned short u[16];
#pragma unroll
            for (int i = 0; i < 16; ++i) u[i] = f2bf(v[i]);
            ((uint4*)adst)[0] = ((uint4*)u)[0];
            ((uint4*)adst)[1] = ((uint4*)u)[1];
        } else {
            uint4 u0, u1;
            if (a_ok) {
                const uint4* p = (const uint4*)(a_src + k0);
                u0 = p[0]; u1 = p[1];
            } else {
                u0 = make_uint4(0, 0, 0, 0);
                u1 = u0;
            }
            ((uint4*)adst)[0] = u0;
            ((uint4*)adst)[1] = u1;
        }
        // ---- stage B (128 cols x 64 k) ----
        {
            const uint4* src = (const uint4*)(b_src + k0);
            uint4* dst = (uint4*)&Bs[brow * GST + bkc];
#pragma unroll
            for (int i = 0; i < 4; ++i) dst[i] = src[i];
        }
        __syncthreads();

#pragma unroll
        for (int ks = 0; ks < 2; ++ks) {
            const int koff = ks * 32 + quad * 8;
            bfrag af = *(const bfrag*)&As[(wave * 16 + ln) * GST + koff];
#pragma unroll
            for (int j = 0; j < 8; ++j) {
                bfrag bf = *(const bfrag*)&Bs[(j * 16 + ln) * GST + koff];
                acc[j] = __builtin_amdgcn_mfma_f32_16x16x32_bf16(af, bf, acc[j], 0, 0, 0);
            }
        }
        __syncthreads();
    }

    // epilogue: row = m0 + wave*16 + quad*4 + r, col = n0 + j*16 + ln
#pragma unroll
    for (int j = 0; j < 8; ++j) {
        const int col = n0 + j * 16 + ln;
        const float bb = bias[col];
#pragma unroll
        for (int r = 0; r < 4; ++r) {
            const int row = m0 + wave * 16 + quad * 4 + r;
            if (row < M) {
                const float v = acc[j][r] + bb;
                if constexpr (std::is_same<CT, unsigned short>::value) {
                    C[(size_t)row * ldc + col] = f2bf(v);
                } else {
                    C[(size_t)row * ldc + col] = v;
                }
            }
        }
    }
}

// ---------------------------------------------------------------------------
// Softmax + locations + bilinear sampling over HEAD-MAJOR bf16 values
// (vb layout [b][h][key][32]). Round-10 winner: block = 16 queries x 4 heads
// (head-half) x 4 dp = 256 threads; (head-half, batch)-major XCD-chunked
// swizzle -> per-XCD gather working set 6.8MB (structural floor at full
// co-residency). FROZEN.
// ---------------------------------------------------------------------------
__global__ __launch_bounds__(256, 4)
void msda_sample_kernel(const float* __restrict__ offattn,  // [BQ][384]
                        const float* __restrict__ rp,
                        const unsigned short* __restrict__ vb,  // [b][h][key][32] bf16
                        unsigned short* __restrict__ outb) {    // (bq,256) bf16
    // bijective XCD chunk swizzle (m204: nwg=900, q=112, r=4), then decode
    // wgid in (head-half, batch)-major order: hh = wgid/450, pos = wgid%450.
    const int orig = blockIdx.x;
    const int xcd = orig & 7;
    const int idx = orig >> 3;
    const int wgid = (xcd < 4) ? (xcd * 113 + idx) : (452 + (xcd - 4) * 112 + idx);
    const int hh = wgid / 450;
    const int pos = wgid - hh * 450;
    const int bq0 = pos * 16;
    const int hb = hh * 4;              // head base for this block
    const int tid = threadIdx.x;

    __shared__ float s_w[16][64];
    __shared__ float s_x[16][64];
    __shared__ float s_y[16][64];

    // load attn logits: 16 q x (4 heads x 16 lp) = 1024 entries
#pragma unroll
    for (int i = 0; i < 4; ++i) {
        const int e = i * 256 + tid;
        const int q = e >> 6, t = e & 63;
        const int h = hb + (t >> 4), lp = t & 15;
        s_w[q][t] = offattn[(size_t)(bq0 + q) * 384 + 256 + h * 16 + lp];
    }
    __syncthreads();

    // softmax per (q, h4): 64 threads, 16 logits each
    if (tid < 64) {
        const int q = tid >> 2, h4 = tid & 3;
        float m = -1e30f;
#pragma unroll
        for (int i = 0; i < 16; ++i) m = fmaxf(m, s_w[q][h4 * 16 + i]);
        float e[16];
        float ssum = 0.f;
#pragma unroll
        for (int i = 0; i < 16; ++i) {
            e[i] = expf(s_w[q][h4 * 16 + i] - m);
            ssum += e[i];
        }
        const float inv = 1.f / ssum;
#pragma unroll
        for (int i = 0; i < 16; ++i) s_w[q][h4 * 16 + i] = e[i] * inv;
    }

    // sampling coordinates (16 q x 64)
#pragma unroll
    for (int i = 0; i < 4; ++i) {
        const int e = i * 256 + tid;
        const int q = e >> 6, t = e & 63;
        const int h = hb + (t >> 4), l = (t >> 2) & 3, p = t & 3;
        const int bq = bq0 + q;
        const float2 off = *(const float2*)(offattn + (size_t)bq * 384 + h * 32 + l * 8 + p * 2);
        const float Wl = (float)c_LW[l];
        const float Hl = (float)c_LH[l];
        const float rx = rp[((size_t)bq * 4 + l) * 2 + 0];
        const float ry = rp[((size_t)bq * 4 + l) * 2 + 1];
        s_x[q][t] = (rx + off.x / Wl) * Wl - 0.5f;   // reference op order
        s_y[q][t] = (ry + off.y / Hl) * Hl - 0.5f;
    }
    __syncthreads();

    const int q = tid >> 4;
    const int s = tid & 15;
    const int h4 = s >> 2;
    const int dp = s & 3;
    const int bq = bq0 + q;
    const int b = bq / QLEN;
    const int h = hb + h4;
    // head-major base: [b][h][key][32], thread reads 8 dims at dp*8
    const unsigned short* vbase = vb + (size_t)(b * 8 + h) * NUM_KEYS * 32 + dp * 8;

    float acc[8];
#pragma unroll
    for (int d = 0; d < 8; ++d) acc[d] = 0.f;

#pragma unroll
    for (int l = 0; l < LEVELS; ++l) {
        const int Hl = c_LH[l];
        const int Wl = c_LW[l];
        const int s0 = c_LS[l];
#pragma unroll 2
        for (int p = 0; p < POINTS; ++p) {
            const int t2 = h4 * 16 + l * 4 + p;
            const float x = s_x[q][t2];
            const float y = s_y[q][t2];
            const float w = s_w[q][t2];
            const float x0f = floorf(x);
            const float y0f = floorf(y);
            const float wx = x - x0f;
            const float wy = y - y0f;
            const int x0 = (int)x0f;
            const int y0 = (int)y0f;
            const float mx0 = ((unsigned)x0 < (unsigned)Wl) ? 1.f : 0.f;
            const float mx1 = ((unsigned)(x0 + 1) < (unsigned)Wl) ? 1.f : 0.f;
            const float my0 = ((unsigned)y0 < (unsigned)Hl) ? 1.f : 0.f;
            const float my1 = ((unsigned)(y0 + 1) < (unsigned)Hl) ? 1.f : 0.f;
            const int xc0 = min(max(x0, 0), Wl - 1);
            const int xc1 = min(max(x0 + 1, 0), Wl - 1);
            const int yc0 = min(max(y0, 0), Hl - 1);
            const int yc1 = min(max(y0 + 1, 0), Hl - 1);
            const float a00 = w * (1.f - wx) * (1.f - wy) * mx0 * my0;
            const float a01 = w * wx * (1.f - wy) * mx1 * my0;
            const float a10 = w * (1.f - wx) * wy * mx0 * my1;
            const float a11 = w * wx * wy * mx1 * my1;
            const size_t k00 = (size_t)(s0 + yc0 * Wl + xc0) * 32;
            const size_t k01 = (size_t)(s0 + yc0 * Wl + xc1) * 32;
            const size_t k10 = (size_t)(s0 + yc1 * Wl + xc0) * 32;
            const size_t k11 = (size_t)(s0 + yc1 * Wl + xc1) * 32;
            const uint4 r00 = *(const uint4*)(vbase + k00);
            const uint4 r01 = *(const uint4*)(vbase + k01);
            const uint4 r10 = *(const uint4*)(vbase + k10);
            const uint4 r11 = *(const uint4*)(vbase + k11);
            const unsigned int w00[4] = {r00.x, r00.y, r00.z, r00.w};
            const unsigned int w01[4] = {r01.x, r01.y, r01.z, r01.w};
            const unsigned int w10[4] = {r10.x, r10.y, r10.z, r10.w};
            const unsigned int w11[4] = {r11.x, r11.y, r11.z, r11.w};
#pragma unroll
            for (int i = 0; i < 4; ++i) {
                const float v00l = bf2f(w00[i] & 0xffffu), v00h = bf2f(w00[i] >> 16);
                const float v01l = bf2f(w01[i] & 0xffffu), v01h = bf2f(w01[i] >> 16);
                const float v10l = bf2f(w10[i] & 0xffffu), v10h = bf2f(w10[i] >> 16);
                const float v11l = bf2f(w11[i] & 0xffffu), v11h = bf2f(w11[i] >> 16);
                acc[i * 2 + 0] = fmaf(a00, v00l, fmaf(a01, v01l, fmaf(a10, v10l, fmaf(a11, v11l, acc[i * 2 + 0]))));
                acc[i * 2 + 1] = fmaf(a00, v00h, fmaf(a01, v01h, fmaf(a10, v10h, fmaf(a11, v11h, acc[i * 2 + 1]))));
            }
        }
    }

    unsigned short o[8];
#pragma unroll
    for (int d = 0; d < 8; ++d) o[d] = f2bf(acc[d]);
    *(uint4*)(outb + (size_t)bq * 256 + h * 32 + dp * 8) = *(uint4*)o;
}

// ---------------------------------------------------------------------------
extern "C" void kernel_launch(void* const* d_in, const int* in_sizes, int n_in,
                              void* d_out, int out_size, void* d_ws, size_t ws_size,
                              hipStream_t stream) {
    const float* query  = (const float*)d_in[0];
    const float* rp     = (const float*)d_in[1];
    const float* value  = (const float*)d_in[2];
    const float* W_off  = (const float*)d_in[5];
    const float* b_off  = (const float*)d_in[6];
    const float* W_attn = (const float*)d_in[7];
    const float* b_attn = (const float*)d_in[8];
    const float* W_val  = (const float*)d_in[9];
    const float* b_val  = (const float*)d_in[10];
    const float* W_out  = (const float*)d_in[11];
    const float* b_out  = (const float*)d_in[12];
    float* out = (float*)d_out;

    // workspace layout
    char* w = (char*)d_ws;
    unsigned short* ws_vb = (unsigned short*)w;                 // [b][h][key][32] bf16
    w += (size_t)MROWS_V * 256 * 2;
    float* ws_offattn = (float*)w;                              // BQ*384 f32
    w += (size_t)BQ * 384 * 4;
    unsigned short* ws_msda = (unsigned short*)w;               // BQ*256 bf16
    w += (size_t)BQ * 256 * 2;
    unsigned short* ws_Wv = (unsigned short*)w;  w += 256 * 256 * 2;   // [n][k]
    unsigned short* ws_Woa = (unsigned short*)w; w += 384 * 256 * 2;   // [n][k]
    unsigned short* ws_Wo = (unsigned short*)w;  w += 256 * 256 * 2;   // [n][k]
    float* ws_boa = (float*)w;                                   // 384 f32

    // 0. merged weight prep (bf16, transposed) + bias concat
    prep_kernel<<<898, 256, 0, stream>>>(W_val, W_off, W_attn, W_out,
                                         b_off, b_attn, ws_Wv, ws_Woa, ws_Wo, ws_boa);

    // 1. value projection -> bf16 head-major (M=106352, N=256), global_load_lds
    gemm_val_stream<<<VBLOCKS, 512, 0, stream>>>(value, ws_Wv, b_val, ws_vb);

    // 2. fused offset+attn projection -> fp32 (M=7200, N=384)
    {
        dim3 grid((BQ + 63) / 64, 3);
        gemm_mfma<float, float><<<grid, 256, 0, stream>>>(
            query, ws_Woa, ws_boa, ws_offattn, BQ, 384);
    }
    // 3. softmax + locations + sampling (16q x 4h blocks, XCD-chunked)
    msda_sample_kernel<<<900, 256, 0, stream>>>(ws_offattn, rp, ws_vb, ws_msda);

    // 4. output projection -> d_out fp32 (M=7200, N=256)
    {
        dim3 grid((BQ + 63) / 64, 2);
        gemm_mfma<unsigned short, float><<<grid, 256, 0, stream>>>(
            ws_msda, ws_Wo, b_out, out, BQ, 256);
    }
}

// Round 12
// 244.102 us; speedup vs baseline: 1.0142x; 1.0142x over previous
//
#include <hip/hip_runtime.h>
#include <hip/hip_bf16.h>
#include <math.h>
#include <type_traits>

// Problem constants (fixed by setup_inputs)
#define BATCH 8
#define QLEN 900
#define HEADS 8
#define LEVELS 4
#define POINTS 4
#define NUM_KEYS 13294
#define BQ (BATCH * QLEN)          // 7200
#define MROWS_V (BATCH * NUM_KEYS) // 106352
#define VTILES (MROWS_V / 16)      // 6647 16-row tiles (exact)
#define VBLOCKS 512
#define TPB 13                     // ceil(6647/512)

__constant__ const int c_LH[4] = {100, 50, 25, 13};
__constant__ const int c_LW[4] = {100, 50, 25, 13};
__constant__ const int c_LS[4] = {0, 10000, 12500, 13125};

typedef __attribute__((ext_vector_type(8))) short bfrag;   // 8 bf16
typedef __attribute__((ext_vector_type(4))) float ffrag;   // 4 fp32 acc

static __device__ __forceinline__ unsigned short f2bf(float f) {
    __hip_bfloat16 h = __float2bfloat16(f);
    return *(unsigned short*)&h;
}
static __device__ __forceinline__ float bf2f(unsigned int u16) {
    unsigned int v = u16 << 16;
    float f;
    __builtin_memcpy(&f, &v, 4);
    return f;
}
static __device__ __forceinline__ unsigned long long pack4bf(float4 v) {
    return (unsigned long long)f2bf(v.x)
         | ((unsigned long long)f2bf(v.y) << 16)
         | ((unsigned long long)f2bf(v.z) << 32)
         | ((unsigned long long)f2bf(v.w) << 48);
}

// ---------------------------------------------------------------------------
// Merged prep: cast+transpose all three weight matrices to bf16 [n][k],
// concat off/attn biases. One launch instead of five.
// ---------------------------------------------------------------------------
__global__ __launch_bounds__(256)
void prep_kernel(const float* __restrict__ W_val, const float* __restrict__ W_off,
                 const float* __restrict__ W_attn, const float* __restrict__ W_out,
                 const float* __restrict__ b_off, const float* __restrict__ b_attn,
                 unsigned short* __restrict__ Wv, unsigned short* __restrict__ Woa,
                 unsigned short* __restrict__ Wo, float* __restrict__ boa) {
    const int id = blockIdx.x * 256 + threadIdx.x;
    if (id < 65536) {
        const int n = id >> 8, k = id & 255;
        Wv[id] = f2bf(W_val[k * 256 + n]);
    } else if (id < 131072) {
        const int t = id - 65536;
        const int n = t >> 8, k = t & 255;
        Woa[t] = f2bf(W_off[k * 256 + n]);
    } else if (id < 163840) {
        const int t = id - 131072;
        const int n = t >> 8, k = t & 255;       // n in 0..127
        Woa[65536 + t] = f2bf(W_attn[k * 128 + n]);
    } else if (id < 229376) {
        const int t = id - 163840;
        const int n = t >> 8, k = t & 255;
        Wo[t] = f2bf(W_out[k * 256 + n]);
    } else if (id < 229760) {
        const int t = id - 229376;
        boa[t] = (t < 256) ? b_off[t] : b_attn[t - 256];
    }
}

// ---------------------------------------------------------------------------
// Value-projection GEMM v9: C = bf16(A @ Wv + bias), HEAD-MAJOR [b][h][key][32].
// Staging = v7 (round-10 proven): reg-staged bf16, 3-deep 8KB LDS ring,
// named L0/L1 reg sets, one raw s_barrier + lgkmcnt(0) per tile, XOR-swizzled
// LDS, 512 thr / 8 waves x 32 cols, b[2][8]=64 VGPR/wave.
// Round-12 change: PACKED EPILOGUE STORES. v7 stored 8x 2-byte scalars per
// thread (4x 32B segments per wave-instr); v8 proved the LOAD path is not
// the limiter, leaving the store path as the last un-probed leg. Lane ln now
// gathers local cols 2ln,2ln+1 via width-16 __shfl from acc[0/1][r], packs
// 2x bf16 -> u32, stores 4B: store instrs halve, each 16-lane group writes
// one contiguous 64B run per (key,r) instead of 2x 32B sectors.
// ---------------------------------------------------------------------------
#define VSTEP(T, LREG)                                                        \
  do {                                                                        \
    const char* abuf = (const char*)&Abuf[0][0] + rb * 8192;                  \
    ffrag acc[2];                                                             \
    _Pragma("unroll")                                                         \
    for (int j_ = 0; j_ < 2; ++j_) acc[j_] = (ffrag){0.f, 0.f, 0.f, 0.f};     \
    _Pragma("unroll")                                                         \
    for (int ks_ = 0; ks_ < 8; ++ks_) {                                       \
      const int ub_ = (ks_ * 64 + quad * 16) ^ ((ln & 7) << 4);               \
      const bfrag af_ = *(const bfrag*)(abuf + ln * 512 + ub_);               \
      _Pragma("unroll")                                                       \
      for (int j_ = 0; j_ < 2; ++j_)                                          \
        acc[j_] = __builtin_amdgcn_mfma_f32_16x16x32_bf16(af_, b[j_][ks_],    \
                                                          acc[j_], 0, 0, 0); \
    }                                                                         \
    if ((T) + 1 < t1) {                                                       \
      const int wb_ = (rb + 1 == 3) ? 0 : rb + 1;                             \
      char* dbuf_ = (char*)&Abuf[0][0] + wb_ * 8192;                          \
      _Pragma("unroll")                                                       \
      for (int i_ = 0; i_ < 2; ++i_)                                          \
        *(unsigned long long*)(dbuf_ + dsoff[i_]) = pack4bf(LREG[i_]);        \
      if ((T) + 3 < t1) {                                                     \
        const float4* ap_ = Af4 + (size_t)((T) + 3) * 1024 + tid;             \
        _Pragma("unroll")                                                     \
        for (int i_ = 0; i_ < 2; ++i_) LREG[i_] = ap_[i_ * 512];              \
      }                                                                       \
    }                                                                         \
    const int rowb_ = (T) * 16 + quad * 4;                                    \
    _Pragma("unroll")                                                         \
    for (int r_ = 0; r_ < 4; ++r_) {                                          \
      const unsigned row_ = rowb_ + r_;                                       \
      const unsigned bb_ = row_ / NUM_KEYS;                                   \
      const unsigned key_ = row_ - bb_ * NUM_KEYS;                            \
      const float a0_ = __shfl(acc[0][r_], (ln * 2) & 15, 16);                \
      const float a1_ = __shfl(acc[1][r_], (ln * 2) & 15, 16);                \
      const float b0_ = __shfl(acc[0][r_], (ln * 2 + 1) & 15, 16);            \
      const float b1_ = __shfl(acc[1][r_], (ln * 2 + 1) & 15, 16);            \
      const float lo_ = (ln < 8) ? a0_ : a1_;                                 \
      const float hi_ = (ln < 8) ? b0_ : b1_;                                 \
      const unsigned pk_ = (unsigned)f2bf(lo_ + bj2.x)                        \
                         | ((unsigned)f2bf(hi_ + bj2.y) << 16);               \
      *(unsigned int*)((char*)C +                                             \
          (((size_t)(bb_ * 8 + hC) * NUM_KEYS + key_) * 64 + ln * 4)) = pk_;  \
    }                                                                         \
    asm volatile("s_waitcnt lgkmcnt(0)" ::: "memory");                        \
    __builtin_amdgcn_s_barrier();                                             \
    rb = (rb + 1 == 3) ? 0 : rb + 1;                                          \
  } while (0)

__global__ __launch_bounds__(512, 4)
void gemm_val_stream(const float* __restrict__ A, const unsigned short* __restrict__ WT,
                     const float* __restrict__ bias, unsigned short* __restrict__ C) {
    __shared__ __align__(16) unsigned short Abuf[3][16 * 256];  // 3 x 8KB bf16 tiles
    const int tid = threadIdx.x;
    const int wave = tid >> 6;
    const int lane = tid & 63;
    const int ln = lane & 15;
    const int quad = lane >> 4;
    const int n0 = wave * 32;           // wave covers one 32-col head slice
    const int hC = n0 >> 5;             // head index (wave-constant)

    // persistent B fragments: 2 n-tiles x 8 k-steps (64 VGPR)
    bfrag b[2][8];
#pragma unroll
    for (int j = 0; j < 2; ++j) {
        const unsigned short* bp = WT + (size_t)(n0 + j * 16 + ln) * 256 + quad * 8;
#pragma unroll
        for (int ks = 0; ks < 8; ++ks) b[j][ks] = *(const bfrag*)(bp + ks * 32);
    }
    // packed-store bias pair: cols n0+2ln, n0+2ln+1
    const float2 bj2 = *(const float2*)&bias[n0 + ln * 2];

    const int t0 = blockIdx.x * TPB;
    const int t1 = min(t0 + TPB, VTILES);
    if (t0 >= t1) return;

    // staging destination offsets: instr i covers float4 index f = i*512+tid
    int dsoff[2];
#pragma unroll
    for (int i = 0; i < 2; ++i) {
        const int f = i * 512 + tid;
        const int r = f >> 6;
        const int cb = (f & 63) * 8;
        dsoff[i] = r * 512 + (cb ^ ((r & 7) << 4));
    }

    const float4* Af4 = (const float4*)A;

    // prologue: stage tile t0 directly, then fill the 2-deep NAMED register
    // pipeline: t0+1 -> L0, t0+2 -> L1.
    float4 L0[2], L1[2];
    {
        const float4* ap = Af4 + (size_t)t0 * 1024 + tid;
        float4 P[2];
#pragma unroll
        for (int i = 0; i < 2; ++i) P[i] = ap[i * 512];
#pragma unroll
        for (int i = 0; i < 2; ++i)
            *(unsigned long long*)((char*)&Abuf[0][0] + dsoff[i]) = pack4bf(P[i]);
    }
    if (t0 + 1 < t1) {
        const float4* ap = Af4 + (size_t)(t0 + 1) * 1024 + tid;
#pragma unroll
        for (int i = 0; i < 2; ++i) L0[i] = ap[i * 512];
    }
    if (t0 + 2 < t1) {
        const float4* ap = Af4 + (size_t)(t0 + 2) * 1024 + tid;
#pragma unroll
        for (int i = 0; i < 2; ++i) L1[i] = ap[i * 512];
    }
    asm volatile("s_waitcnt lgkmcnt(0)" ::: "memory");
    __builtin_amdgcn_s_barrier();

    int rb = 0;
    int t = t0;
    while (t + 1 < t1) {
        VSTEP(t, L0);
        VSTEP(t + 1, L1);
        t += 2;
    }
    if (t < t1) VSTEP(t, L0);
}

// ---------------------------------------------------------------------------
// bf16-MFMA GEMM: C[M,N] = bf16(A[M,256]) @ WT^T + bias.
// WT is [N][256] bf16 (pre-transposed). BM=64, BN=128, BK=64, 256 thr = 4 waves.
// Used for the offattn GEMM and the out-projection.
// ---------------------------------------------------------------------------
#define GST 72

template <typename AT, typename CT>
__global__ __launch_bounds__(256)
void gemm_mfma(const AT* __restrict__ A, const unsigned short* __restrict__ WT,
               const float* __restrict__ bias, CT* __restrict__ C,
               int M, int ldc) {
    __shared__ unsigned short As[64 * GST];
    __shared__ unsigned short Bs[128 * GST];
    const int tid = threadIdx.x;
    const int wave = tid >> 6;
    const int lane = tid & 63;
    const int ln = lane & 15;
    const int quad = lane >> 4;
    const int m0 = blockIdx.x * 64;
    const int n0 = blockIdx.y * 128;

    ffrag acc[8];
#pragma unroll
    for (int j = 0; j < 8; ++j) acc[j] = (ffrag){0.f, 0.f, 0.f, 0.f};

    const int ar = tid >> 2;            // A row in tile (0..63)
    const int akc = (tid & 3) * 16;     // A k-chunk (16 elems)
    const int brow = tid >> 1;          // B col in tile (0..127)
    const int bkc = (tid & 1) * 32;     // B k-chunk (32 elems)
    const bool a_ok = (m0 + ar) < M;
    const AT* a_src = A + (size_t)(m0 + ar) * 256 + akc;
    const unsigned short* b_src = WT + (size_t)(n0 + brow) * 256 + bkc;

    for (int k0 = 0; k0 < 256; k0 += 64) {
        // ---- stage A (64 x 64, -> bf16) ----
        unsigned short* adst = &As[ar * GST + akc];
        if constexpr (std::is_same<AT, float>::value) {
            float4 f0, f1, f2, f3;
            if (a_ok) {
                const float4* p = (const float4*)(a_src + k0);
                f0 = p[0]; f1 = p[1]; f2 = p[2]; f3 = p[3];
            } else {
                f0 = make_float4(0.f, 0.f, 0.f, 0.f);
                f1 = f0; f2 = f0; f3 = f0;
            }
            float v[16] = {f0.x, f0.y, f0.z, f0.w, f1.x, f1.y, f1.z, f1.w,
                           f2.x, f2.y, f2.z, f2.w, f3.x, f3.y, f3.z, f3.w};
            unsigned short u[16];
#pragma unroll
            for (int i = 0; i < 16; ++i) u[i] = f2bf(v[i]);
            ((uint4*)adst)[0] = ((uint4*)u)[0];
            ((uint4*)adst)[1] = ((uint4*)u)[1];
        } else {
            uint4 u0, u1;
            if (a_ok) {
                const uint4* p = (const uint4*)(a_src + k0);
                u0 = p[0]; u1 = p[1];
            } else {
                u0 = make_uint4(0, 0, 0, 0);
                u1 = u0;
            }
            ((uint4*)adst)[0] = u0;
            ((uint4*)adst)[1] = u1;
        }
        // ---- stage B (128 cols x 64 k) ----
        {
            const uint4* src = (const uint4*)(b_src + k0);
            uint4* dst = (uint4*)&Bs[brow * GST + bkc];
#pragma unroll
            for (int i = 0; i < 4; ++i) dst[i] = src[i];
        }
        __syncthreads();

#pragma unroll
        for (int ks = 0; ks < 2; ++ks) {
            const int koff = ks * 32 + quad * 8;
            bfrag af = *(const bfrag*)&As[(wave * 16 + ln) * GST + koff];
#pragma unroll
            for (int j = 0; j < 8; ++j) {
                bfrag bf = *(const bfrag*)&Bs[(j * 16 + ln) * GST + koff];
                acc[j] = __builtin_amdgcn_mfma_f32_16x16x32_bf16(af, bf, acc[j], 0, 0, 0);
            }
        }
        __syncthreads();
    }

    // epilogue: row = m0 + wave*16 + quad*4 + r, col = n0 + j*16 + ln
#pragma unroll
    for (int j = 0; j < 8; ++j) {
        const int col = n0 + j * 16 + ln;
        const float bb = bias[col];
#pragma unroll
        for (int r = 0; r < 4; ++r) {
            const int row = m0 + wave * 16 + quad * 4 + r;
            if (row < M) {
                const float v = acc[j][r] + bb;
                if constexpr (std::is_same<CT, unsigned short>::value) {
                    C[(size_t)row * ldc + col] = f2bf(v);
                } else {
                    C[(size_t)row * ldc + col] = v;
                }
            }
        }
    }
}

// ---------------------------------------------------------------------------
// Softmax + locations + bilinear sampling over HEAD-MAJOR bf16 values
// (vb layout [b][h][key][32]). Round-10 winner: block = 16 queries x 4 heads
// (head-half) x 4 dp = 256 threads; (head-half, batch)-major XCD-chunked
// swizzle -> per-XCD gather working set 6.8MB (structural floor at full
// co-residency). FROZEN.
// ---------------------------------------------------------------------------
__global__ __launch_bounds__(256, 4)
void msda_sample_kernel(const float* __restrict__ offattn,  // [BQ][384]
                        const float* __restrict__ rp,
                        const unsigned short* __restrict__ vb,  // [b][h][key][32] bf16
                        unsigned short* __restrict__ outb) {    // (bq,256) bf16
    // bijective XCD chunk swizzle (m204: nwg=900, q=112, r=4), then decode
    // wgid in (head-half, batch)-major order: hh = wgid/450, pos = wgid%450.
    const int orig = blockIdx.x;
    const int xcd = orig & 7;
    const int idx = orig >> 3;
    const int wgid = (xcd < 4) ? (xcd * 113 + idx) : (452 + (xcd - 4) * 112 + idx);
    const int hh = wgid / 450;
    const int pos = wgid - hh * 450;
    const int bq0 = pos * 16;
    const int hb = hh * 4;              // head base for this block
    const int tid = threadIdx.x;

    __shared__ float s_w[16][64];
    __shared__ float s_x[16][64];
    __shared__ float s_y[16][64];

    // load attn logits: 16 q x (4 heads x 16 lp) = 1024 entries
#pragma unroll
    for (int i = 0; i < 4; ++i) {
        const int e = i * 256 + tid;
        const int q = e >> 6, t = e & 63;
        const int h = hb + (t >> 4), lp = t & 15;
        s_w[q][t] = offattn[(size_t)(bq0 + q) * 384 + 256 + h * 16 + lp];
    }
    __syncthreads();

    // softmax per (q, h4): 64 threads, 16 logits each
    if (tid < 64) {
        const int q = tid >> 2, h4 = tid & 3;
        float m = -1e30f;
#pragma unroll
        for (int i = 0; i < 16; ++i) m = fmaxf(m, s_w[q][h4 * 16 + i]);
        float e[16];
        float ssum = 0.f;
#pragma unroll
        for (int i = 0; i < 16; ++i) {
            e[i] = expf(s_w[q][h4 * 16 + i] - m);
            ssum += e[i];
        }
        const float inv = 1.f / ssum;
#pragma unroll
        for (int i = 0; i < 16; ++i) s_w[q][h4 * 16 + i] = e[i] * inv;
    }

    // sampling coordinates (16 q x 64)
#pragma unroll
    for (int i = 0; i < 4; ++i) {
        const int e = i * 256 + tid;
        const int q = e >> 6, t = e & 63;
        const int h = hb + (t >> 4), l = (t >> 2) & 3, p = t & 3;
        const int bq = bq0 + q;
        const float2 off = *(const float2*)(offattn + (size_t)bq * 384 + h * 32 + l * 8 + p * 2);
        const float Wl = (float)c_LW[l];
        const float Hl = (float)c_LH[l];
        const float rx = rp[((size_t)bq * 4 + l) * 2 + 0];
        const float ry = rp[((size_t)bq * 4 + l) * 2 + 1];
        s_x[q][t] = (rx + off.x / Wl) * Wl - 0.5f;   // reference op order
        s_y[q][t] = (ry + off.y / Hl) * Hl - 0.5f;
    }
    __syncthreads();

    const int q = tid >> 4;
    const int s = tid & 15;
    const int h4 = s >> 2;
    const int dp = s & 3;
    const int bq = bq0 + q;
    const int b = bq / QLEN;
    const int h = hb + h4;
    // head-major base: [b][h][key][32], thread reads 8 dims at dp*8
    const unsigned short* vbase = vb + (size_t)(b * 8 + h) * NUM_KEYS * 32 + dp * 8;

    float acc[8];
#pragma unroll
    for (int d = 0; d < 8; ++d) acc[d] = 0.f;

#pragma unroll
    for (int l = 0; l < LEVELS; ++l) {
        const int Hl = c_LH[l];
        const int Wl = c_LW[l];
        const int s0 = c_LS[l];
#pragma unroll 2
        for (int p = 0; p < POINTS; ++p) {
            const int t2 = h4 * 16 + l * 4 + p;
            const float x = s_x[q][t2];
            const float y = s_y[q][t2];
            const float w = s_w[q][t2];
            const float x0f = floorf(x);
            const float y0f = floorf(y);
            const float wx = x - x0f;
            const float wy = y - y0f;
            const int x0 = (int)x0f;
            const int y0 = (int)y0f;
            const float mx0 = ((unsigned)x0 < (unsigned)Wl) ? 1.f : 0.f;
            const float mx1 = ((unsigned)(x0 + 1) < (unsigned)Wl) ? 1.f : 0.f;
            const float my0 = ((unsigned)y0 < (unsigned)Hl) ? 1.f : 0.f;
            const float my1 = ((unsigned)(y0 + 1) < (unsigned)Hl) ? 1.f : 0.f;
            const int xc0 = min(max(x0, 0), Wl - 1);
            const int xc1 = min(max(x0 + 1, 0), Wl - 1);
            const int yc0 = min(max(y0, 0), Hl - 1);
            const int yc1 = min(max(y0 + 1, 0), Hl - 1);
            const float a00 = w * (1.f - wx) * (1.f - wy) * mx0 * my0;
            const float a01 = w * wx * (1.f - wy) * mx1 * my0;
            const float a10 = w * (1.f - wx) * wy * mx0 * my1;
            const float a11 = w * wx * wy * mx1 * my1;
            const size_t k00 = (size_t)(s0 + yc0 * Wl + xc0) * 32;
            const size_t k01 = (size_t)(s0 + yc0 * Wl + xc1) * 32;
            const size_t k10 = (size_t)(s0 + yc1 * Wl + xc0) * 32;
            const size_t k11 = (size_t)(s0 + yc1 * Wl + xc1) * 32;
            const uint4 r00 = *(const uint4*)(vbase + k00);
            const uint4 r01 = *(const uint4*)(vbase + k01);
            const uint4 r10 = *(const uint4*)(vbase + k10);
            const uint4 r11 = *(const uint4*)(vbase + k11);
            const unsigned int w00[4] = {r00.x, r00.y, r00.z, r00.w};
            const unsigned int w01[4] = {r01.x, r01.y, r01.z, r01.w};
            const unsigned int w10[4] = {r10.x, r10.y, r10.z, r10.w};
            const unsigned int w11[4] = {r11.x, r11.y, r11.z, r11.w};
#pragma unroll
            for (int i = 0; i < 4; ++i) {
                const float v00l = bf2f(w00[i] & 0xffffu), v00h = bf2f(w00[i] >> 16);
                const float v01l = bf2f(w01[i] & 0xffffu), v01h = bf2f(w01[i] >> 16);
                const float v10l = bf2f(w10[i] & 0xffffu), v10h = bf2f(w10[i] >> 16);
                const float v11l = bf2f(w11[i] & 0xffffu), v11h = bf2f(w11[i] >> 16);
                acc[i * 2 + 0] = fmaf(a00, v00l, fmaf(a01, v01l, fmaf(a10, v10l, fmaf(a11, v11l, acc[i * 2 + 0]))));
                acc[i * 2 + 1] = fmaf(a00, v00h, fmaf(a01, v01h, fmaf(a10, v10h, fmaf(a11, v11h, acc[i * 2 + 1]))));
            }
        }
    }

    unsigned short o[8];
#pragma unroll
    for (int d = 0; d < 8; ++d) o[d] = f2bf(acc[d]);
    *(uint4*)(outb + (size_t)bq * 256 + h * 32 + dp * 8) = *(uint4*)o;
}

// ---------------------------------------------------------------------------
extern "C" void kernel_launch(void* const* d_in, const int* in_sizes, int n_in,
                              void* d_out, int out_size, void* d_ws, size_t ws_size,
                              hipStream_t stream) {
    const float* query  = (const float*)d_in[0];
    const float* rp     = (const float*)d_in[1];
    const float* value  = (const float*)d_in[2];
    const float* W_off  = (const float*)d_in[5];
    const float* b_off  = (const float*)d_in[6];
    const float* W_attn = (const float*)d_in[7];
    const float* b_attn = (const float*)d_in[8];
    const float* W_val  = (const float*)d_in[9];
    const float* b_val  = (const float*)d_in[10];
    const float* W_out  = (const float*)d_in[11];
    const float* b_out  = (const float*)d_in[12];
    float* out = (float*)d_out;

    // workspace layout
    char* w = (char*)d_ws;
    unsigned short* ws_vb = (unsigned short*)w;                 // [b][h][key][32] bf16
    w += (size_t)MROWS_V * 256 * 2;
    float* ws_offattn = (float*)w;                              // BQ*384 f32
    w += (size_t)BQ * 384 * 4;
    unsigned short* ws_msda = (unsigned short*)w;               // BQ*256 bf16
    w += (size_t)BQ * 256 * 2;
    unsigned short* ws_Wv = (unsigned short*)w;  w += 256 * 256 * 2;   // [n][k]
    unsigned short* ws_Woa = (unsigned short*)w; w += 384 * 256 * 2;   // [n][k]
    unsigned short* ws_Wo = (unsigned short*)w;  w += 256 * 256 * 2;   // [n][k]
    float* ws_boa = (float*)w;                                   // 384 f32

    // 0. merged weight prep (bf16, transposed) + bias concat
    prep_kernel<<<898, 256, 0, stream>>>(W_val, W_off, W_attn, W_out,
                                         b_off, b_attn, ws_Wv, ws_Woa, ws_Wo, ws_boa);

    // 1. value projection -> bf16 head-major (M=106352, N=256), 512-thr blocks
    gemm_val_stream<<<VBLOCKS, 512, 0, stream>>>(value, ws_Wv, b_val, ws_vb);

    // 2. fused offset+attn projection -> fp32 (M=7200, N=384)
    {
        dim3 grid((BQ + 63) / 64, 3);
        gemm_mfma<float, float><<<grid, 256, 0, stream>>>(
            query, ws_Woa, ws_boa, ws_offattn, BQ, 384);
    }
    // 3. softmax + locations + sampling (16q x 4h blocks, XCD-chunked)
    msda_sample_kernel<<<900, 256, 0, stream>>>(ws_offattn, rp, ws_vb, ws_msda);

    // 4. output projection -> d_out fp32 (M=7200, N=256)
    {
        dim3 grid((BQ + 63) / 64, 2);
        gemm_mfma<unsigned short, float><<<grid, 256, 0, stream>>>(
            ws_msda, ws_Wo, b_out, out, BQ, 256);
    }
}